// Round 21
// baseline (979.238 us; speedup 1.0000x reference)
//
#include <hip/hip_runtime.h>
#include <cmath>

#define NB 8
#define NN 20000
#define ND 128
#define NE_TOT 192000   /* 3 edge sets * 64000 edges, contiguous per batch */

#define GSZ 640                     /* src nodes per group */
#define NG 32                       /* NG*GSZ = 20480 >= NN */
#define ECHUNK 8000                 /* edges per bucketing chunk */
#define NCHUNK 24                   /* NE_TOT / ECHUNK, exact */
#define CSUB 384                    /* per-(b,g,chunk) sub-slot capacity (+8.6 sigma) */
#define FIX (NCHUNK * CSUB)         /* 9216 entries per (b,g) */
#define KPT (FIX / 1024)            /* 9 loads per slot-build thread */
#define JMAX 40                     /* slots per node; P(deg>40) ~ 1e-13 */

#define PNB 157                     /* pass blocks: 157*128 = 20096 >= NN */
#define PBS 256                     /* rows per pool block (R18 form) */
#define NPB ((NN + PBS - 1) / PBS)  /* 79 */

#define PIPE_REPS 9                 /* instrumentation: 1 cold + 8 warm replays */

// weight ping-pong + build metadata + packed bucket + ushort slot table + partials
__device__ float          g_w0[NB * NN];
__device__ float          g_w1[NB * NN];
__device__ int            g_ccnt[NB][NCHUNK][NG];          // 24.6 KB
__device__ unsigned int   g_bucket[(size_t)NB * NG * FIX]; // 9.4 MB (dst | srcl<<16)
__device__ unsigned short g_degU[NB * NN];                 // 320 KB
__device__ unsigned short g_pT[(size_t)NB * JMAX * NN];    // 12.8 MB: pT[b][j][n]=dst
__device__ float          g_ppart[NB * NPB * ND];          // 323 KB

// ---- kernel 1: bin edges into fixed per-chunk sub-slots ----
__global__ void distK(const int* __restrict__ edges) {
    __shared__ int cur[NG];
    const int b = blockIdx.x / NCHUNK, c = blockIdx.x % NCHUNK;
    const int t = threadIdx.x;  // 256
    if (t < NG) cur[t] = 0;
    __syncthreads();
    const int2* __restrict__ ep =
        (const int2*)edges + (size_t)b * NE_TOT + (size_t)c * ECHUNK;
    for (int i = t; i < ECHUNK; i += 256) {
        const int2 e = ep[i];                 // e.x = dst, e.y = src
        const int g = (unsigned)e.y / GSZ;
        const int pos = atomicAdd(&cur[g], 1);
        if (pos < CSUB)                       // P(overflow) ~ 1e-14; guard only
            g_bucket[((size_t)(b * NG + g)) * FIX + c * CSUB + pos] =
                (unsigned)e.x | ((unsigned)(e.y - g * GSZ) << 16);
    }
    __syncthreads();
    if (t < NG) g_ccnt[b][c][t] = min(cur[t], CSUB);
}

// ---- kernel 2: per-(b,g) degree hist + scatter into (node, slot) cells ----
__global__ void __launch_bounds__(1024)
slotK() {
    __shared__ int hist[GSZ];
    __shared__ int cur[GSZ];
    __shared__ int ccnt[NCHUNK];
    const int b = blockIdx.y, g = blockIdx.x;
    const int t = threadIdx.x;            // 1024

    const unsigned* __restrict__ bk = g_bucket + (size_t)(b * NG + g) * FIX + t;
    unsigned e[KPT];
#pragma unroll
    for (int k = 0; k < KPT; ++k) e[k] = bk[k * 1024];

    if (t < GSZ) { hist[t] = 0; cur[t] = 0; }
    if (t < NCHUNK) ccnt[t] = g_ccnt[b][t][g];
    __syncthreads();

    bool val[KPT];
#pragma unroll
    for (int k = 0; k < KPT; ++k) {
        const int p = k * 1024 + t;
        const int c = p / CSUB;           // const-div -> magic mul
        val[k] = (p - c * CSUB) < ccnt[c];
        if (val[k]) atomicAdd(&hist[e[k] >> 16], 1);
    }
    __syncthreads();

    if (t < GSZ) {
        const int node = g * GSZ + t;
        if (node < NN) {
            const int d = hist[t];
            g_degU[b * NN + node] = (unsigned short)min(d, JMAX);
            g_w1[b * NN + node]   = 1.0f + (float)d;   // pass 1 for free
        }
    }
    __syncthreads();

    const size_t colbase = (size_t)b * JMAX * NN + g * GSZ;
#pragma unroll
    for (int k = 0; k < KPT; ++k)
        if (val[k]) {
            const int y = e[k] >> 16;
            const int j = atomicAdd(&cur[y], 1);
            if (j < JMAX)
                g_pT[colbase + (size_t)j * NN + y] = (unsigned short)(e[k] & 0xFFFF);
        }
}

// ---- kernels 3-5: high-occupancy pass: 4 j-groups x 128 nodes per block ----
template<int SRC>   // SRC=1: read g_w1 write g_w0; SRC=0: reverse
__global__ void __launch_bounds__(512)
passHO() {
    __shared__ float sh[512];
    const int b  = blockIdx.y;
    const int nl = threadIdx.x & 127;
    const int jg = threadIdx.x >> 7;      // 0..3
    const int n  = blockIdx.x * 128 + nl;
    const float* __restrict__ wp = (SRC ? g_w1 : g_w0) + b * NN;
    float* __restrict__ wn       = (SRC ? g_w0 : g_w1) + b * NN;

    float partial = 0.0f;
    if (n < NN) {
        const int deg = g_degU[b * NN + n];
        const unsigned short* __restrict__ pT = g_pT + (size_t)b * JMAX * NN + n;
#pragma unroll
        for (int jj = 0; jj < 10; ++jj) {
            const int j = jg + 4 * jj;
            if (j < deg) partial += wp[pT[(size_t)j * NN]];
        }
    }
    sh[threadIdx.x] = partial;
    __syncthreads();
    if (jg == 0 && n < NN)
        wn[n] = wp[n] + ((sh[nl] + sh[128 + nl]) + (sh[256 + nl] + sh[384 + nl]));
}

// ---- kernel 6: final pass (slot form) fused with weighted pool (R18 form) ----
__global__ void __launch_bounds__(256)
pass5poolK(const float* __restrict__ nodes) {
    __shared__ float w5s[PBS];
    __shared__ __align__(16) float4 red[256];
    const int b = blockIdx.y, p = blockIdx.x;
    const int t = threadIdx.x;
    const int n0 = p * PBS;
    const int n  = n0 + t;
    const float* __restrict__ wp = g_w0 + b * NN;   // w4 lives in g_w0

    float w5 = 0.0f;
    if (n < NN) {
        const int deg = g_degU[b * NN + n];
        const unsigned short* __restrict__ pT = g_pT + (size_t)b * JMAX * NN + n;
        float sum = wp[n];
#pragma unroll
        for (int j = 0; j < JMAX; ++j)
            if (j < deg) sum += wp[pT[(size_t)j * NN]];
        w5 = sum;
    }
    w5s[t] = w5;
    __syncthreads();

    // pool rows n0..n0+255: part[d] = sum w5[row] * nodes[b][row][d]
    const int dslot = t & 31, rg = t >> 5;    // 32 f4-cols x 8 row-groups
    const int nrows = min(PBS, NN - n0);
    const float4* __restrict__ base = (const float4*)(nodes + (size_t)b * NN * ND);
    float4 aA = {0.f, 0.f, 0.f, 0.f}, aB = {0.f, 0.f, 0.f, 0.f};
    int row = rg;
    for (; row + 8 < nrows; row += 16) {
        const float wA = w5s[row], wB = w5s[row + 8];
        const float4 vA = base[(size_t)(n0 + row) * 32 + dslot];
        const float4 vB = base[(size_t)(n0 + row + 8) * 32 + dslot];
        aA.x += wA * vA.x; aA.y += wA * vA.y; aA.z += wA * vA.z; aA.w += wA * vA.w;
        aB.x += wB * vB.x; aB.y += wB * vB.y; aB.z += wB * vB.z; aB.w += wB * vB.w;
    }
    if (row < nrows) {
        const float wA = w5s[row];
        const float4 vA = base[(size_t)(n0 + row) * 32 + dslot];
        aA.x += wA * vA.x; aA.y += wA * vA.y; aA.z += wA * vA.z; aA.w += wA * vA.w;
    }
    float4 s4;
    s4.x = aA.x + aB.x; s4.y = aA.y + aB.y; s4.z = aA.z + aB.z; s4.w = aA.w + aB.w;
    red[t] = s4;
    __syncthreads();
    if (t < 32) {
        float4 s = red[t];
        for (int q = 1; q < 8; ++q) {
            const float4 o = red[q * 32 + t];
            s.x += o.x; s.y += o.y; s.z += o.z; s.w += o.w;
        }
        ((float4*)g_ppart)[((size_t)b * NPB + p) * 32 + t] = s;
    }
}

// ---- kernel 7: reduce NPB partials per batch + full head, one block ----
__global__ void reduceHeadK(const float* __restrict__ ptype,
                            const float* __restrict__ w1, const float* __restrict__ b1,
                            const float* __restrict__ w2, const float* __restrict__ b2,
                            const float* __restrict__ w3, const float* __restrict__ b3,
                            float* __restrict__ out) {
    __shared__ float sx[NB][ND + 1];
    __shared__ float h1s[NB][80];
    __shared__ float h2s[NB][80];
    const int t = threadIdx.x;          // 1024 == NB * ND
    const int b = t >> 7, d = t & 127;

    float s = 0.0f;
    for (int j = 0; j < NPB; ++j)
        s += g_ppart[((size_t)b * NPB + j) * ND + d];

    float y = logf(s);
    if (isnan(y)) y = 0.0f;             // nan -> 0
    y = fmaxf(y, 0.0f);                 // relu (folds -inf -> 0)
    sx[b][d] = y;
    __syncthreads();

    if (t < NB) {
        float fm = -INFINITY;
        for (int dd = 0; dd < ND; ++dd) {
            const float v = sx[t][dd];
            if (!isinf(v)) fm = fmaxf(fm, v);
        }
        for (int dd = 0; dd < ND; ++dd)
            if (isinf(sx[t][dd])) sx[t][dd] = fm;   // +inf -> finite_max
        sx[t][ND] = ptype[t];
    }
    __syncthreads();

    if (t < NB * 80) {
        const int bb = t / 80, j = t - bb * 80;
        float v = b1[j];
        for (int k = 0; k < ND + 1; ++k) v += sx[bb][k] * w1[k * 80 + j];
        h1s[bb][j] = v > 0.0f ? v : 0.01f * v;      // leaky_relu
    }
    __syncthreads();

    if (t < NB * 80) {
        const int bb = t / 80, j = t - bb * 80;
        float v = b2[j];
        for (int k = 0; k < 80; ++k) v += h1s[bb][k] * w2[k * 80 + j];
        h2s[bb][j] = v > 0.0f ? v : 0.01f * v;
    }
    __syncthreads();

    if (t < NB * 10) {
        const int bb = t / 10, j = t - bb * 10;
        float v = b3[j];
        for (int k = 0; k < 80; ++k) v += h2s[bb][k] * w3[k * 10 + j];
        out[bb * 10 + j] = v;
    }
}

extern "C" void kernel_launch(void* const* d_in, const int* in_sizes, int n_in,
                              void* d_out, int out_size, void* d_ws, size_t ws_size,
                              hipStream_t stream) {
    const float* nodes = (const float*)d_in[0];
    const float* ptype = (const float*)d_in[1];
    const float* w1    = (const float*)d_in[2];
    const float* b1    = (const float*)d_in[3];
    const float* w2    = (const float*)d_in[4];
    const float* b2    = (const float*)d_in[5];
    const float* w3    = (const float*)d_in[6];
    const float* b3    = (const float*)d_in[7];
    const int*   edges = (const int*)d_in[8];
    float* out = (float*)d_out;

    // INSTRUMENTATION: run the (idempotent, deterministic) pipeline 9 times.
    // Rep 1 = production conditions (cold/contended); reps 2-9 = warm, no fills.
    // warm_pipeline = (dur_us - cold)/8 discriminates environment vs kernel cost.
    for (int r = 0; r < PIPE_REPS; ++r) {
        distK<<<NB * NCHUNK, 256, 0, stream>>>(edges);
        slotK<<<dim3(NG, NB), 1024, 0, stream>>>();
        passHO<1><<<dim3(PNB, NB), 512, 0, stream>>>();
        passHO<0><<<dim3(PNB, NB), 512, 0, stream>>>();
        passHO<1><<<dim3(PNB, NB), 512, 0, stream>>>();
        pass5poolK<<<dim3(NPB, NB), PBS, 0, stream>>>(nodes);
        reduceHeadK<<<1, 1024, 0, stream>>>(ptype, w1, b1, w2, b2, w3, b3, out);
    }
}

// Round 22
// 110.419 us; speedup vs baseline: 8.8684x; 8.8684x over previous
//
#include <hip/hip_runtime.h>
#include <cmath>

#define NB 8
#define NN 20000
#define ND 128
#define NE_TOT 192000   /* 3 edge sets * 64000 edges, contiguous per batch */

#define GSZ 640                     /* src nodes per group */
#define NG 32                       /* NG*GSZ = 20480 >= NN */
#define ECHUNK 8000                 /* edges per bucketing chunk */
#define NCHUNK 24                   /* NE_TOT / ECHUNK, exact */
#define CSUB 384                    /* per-(b,g,chunk) sub-slot capacity (+8.6 sigma) */
#define FIX (NCHUNK * CSUB)         /* 9216 entries per (b,g) */
#define KPT (FIX / 1024)            /* 9 loads per slot-build thread */
#define JMAX 40                     /* slots per node; P(deg>40) ~ 1e-13 */

#define PNB 157                     /* pass blocks: 157*128 = 20096 >= NN */
#define PBS 256                     /* rows per pool block */
#define NPB ((NN + PBS - 1) / PBS)  /* 79 */

// weight ping-pong + build metadata + packed bucket + ushort slot table + partials
__device__ float          g_w0[NB * NN];
__device__ float          g_w1[NB * NN];
__device__ int            g_ccnt[NB][NCHUNK][NG];          // 24.6 KB
__device__ unsigned int   g_bucket[(size_t)NB * NG * FIX]; // 9.4 MB (dst | srcl<<16)
__device__ unsigned short g_degU[NB * NN];                 // 320 KB
__device__ unsigned short g_pT[(size_t)NB * JMAX * NN];    // 12.8 MB: pT[b][j][n]=dst
__device__ float          g_ppart[NB * NPB * ND];          // 323 KB

// ---- kernel 1: bin edges in LDS, dump bucket with fully coalesced stores ----
__global__ void __launch_bounds__(256)
distK(const int* __restrict__ edges) {
    __shared__ unsigned sbuf[NG][CSUB];   // 49152 B staging
    __shared__ int cur[NG];
    const int b = blockIdx.x / NCHUNK, c = blockIdx.x % NCHUNK;
    const int t = threadIdx.x;  // 256
    if (t < NG) cur[t] = 0;
    __syncthreads();
    const int2* __restrict__ ep =
        (const int2*)edges + (size_t)b * NE_TOT + (size_t)c * ECHUNK;
    for (int i = t; i < ECHUNK; i += 256) {
        const int2 e = ep[i];                 // e.x = dst, e.y = src
        const int g = (unsigned)e.y / GSZ;
        const int pos = atomicAdd(&cur[g], 1);
        if (pos < CSUB)                       // P(overflow) ~ 1e-14; guard only
            sbuf[g][pos] = (unsigned)e.x | ((unsigned)(e.y - g * GSZ) << 16);
    }
    __syncthreads();
    // coalesced dump (unused cells = garbage, masked later by g_ccnt)
    const unsigned* __restrict__ s = &sbuf[0][0];
    for (int idx = t; idx < NG * CSUB; idx += 256) {
        const int g = idx / CSUB, pos = idx - g * CSUB;
        g_bucket[((size_t)(b * NG + g)) * FIX + c * CSUB + pos] = s[idx];
    }
    if (t < NG) g_ccnt[b][c][t] = min(cur[t], CSUB);
}

// ---- kernel 2: degree hist + slot table built in LDS, dumped coalesced ----
__global__ void __launch_bounds__(1024)
slotK() {
    __shared__ unsigned short tbl[JMAX][GSZ];   // 51200 B staging
    __shared__ int hist[GSZ];
    __shared__ int cur[GSZ];
    __shared__ int ccnt[NCHUNK];
    const int b = blockIdx.y, g = blockIdx.x;
    const int t = threadIdx.x;            // 1024

    const unsigned* __restrict__ bk = g_bucket + (size_t)(b * NG + g) * FIX + t;
    unsigned e[KPT];
#pragma unroll
    for (int k = 0; k < KPT; ++k) e[k] = bk[k * 1024];

    if (t < GSZ) { hist[t] = 0; cur[t] = 0; }
    if (t < NCHUNK) ccnt[t] = g_ccnt[b][t][g];
    __syncthreads();

    bool val[KPT];
#pragma unroll
    for (int k = 0; k < KPT; ++k) {
        const int p = k * 1024 + t;
        const int c = p / CSUB;           // const-div -> magic mul
        val[k] = (p - c * CSUB) < ccnt[c];
        if (val[k]) atomicAdd(&hist[e[k] >> 16], 1);
    }
    __syncthreads();

    if (t < GSZ) {
        const int node = g * GSZ + t;
        if (node < NN) {
            const int d = hist[t];
            g_degU[b * NN + node] = (unsigned short)min(d, JMAX);
            g_w1[b * NN + node]   = 1.0f + (float)d;   // pass 1 for free
        }
    }
    __syncthreads();

    // scatter into LDS table (cheap), not into global
#pragma unroll
    for (int k = 0; k < KPT; ++k)
        if (val[k]) {
            const int y = e[k] >> 16;
            const int j = atomicAdd(&cur[y], 1);
            if (j < JMAX)
                tbl[j][y] = (unsigned short)(e[k] & 0xFFFF);
        }
    __syncthreads();

    // coalesced dump, uint-granular; clamp last group's columns to NN
    const size_t gbase = (size_t)b * JMAX * NN + (size_t)g * GSZ;
    const int cols2 = min(GSZ, NN - g * GSZ) >> 1;   // uints per row (80 or 320)
    for (int idx = t; idx < JMAX * (GSZ / 2); idx += 1024) {
        const int j = idx / (GSZ / 2), q = idx - j * (GSZ / 2);
        if (q < cols2)
            ((unsigned*)(g_pT + gbase + (size_t)j * NN))[q] =
                ((const unsigned*)&tbl[j][0])[q];
    }
}

// ---- kernels 3-5: high-occupancy pass: 4 j-groups x 128 nodes per block ----
// All per-node sums are integer-valued -> exact in any order (deterministic).
template<int SRC>   // SRC=1: read g_w1 write g_w0; SRC=0: reverse
__global__ void __launch_bounds__(512)
passHO() {
    __shared__ float sh[512];
    const int b  = blockIdx.y;
    const int nl = threadIdx.x & 127;
    const int jg = threadIdx.x >> 7;      // 0..3
    const int n  = blockIdx.x * 128 + nl;
    const float* __restrict__ wp = (SRC ? g_w1 : g_w0) + b * NN;
    float* __restrict__ wn       = (SRC ? g_w0 : g_w1) + b * NN;

    float partial = 0.0f;
    if (n < NN) {
        const int deg = g_degU[b * NN + n];
        const unsigned short* __restrict__ pT = g_pT + (size_t)b * JMAX * NN + n;
#pragma unroll
        for (int jj = 0; jj < 10; ++jj) {
            const int j = jg + 4 * jj;
            if (j < deg) partial += wp[pT[(size_t)j * NN]];
        }
    }
    sh[threadIdx.x] = partial;
    __syncthreads();
    if (jg == 0 && n < NN)
        wn[n] = wp[n] + ((sh[nl] + sh[128 + nl]) + (sh[256 + nl] + sh[384 + nl]));
}

// ---- kernel 6: final pass (slot form) fused with weighted pool ----
__global__ void __launch_bounds__(256)
pass5poolK(const float* __restrict__ nodes) {
    __shared__ float w5s[PBS];
    __shared__ __align__(16) float4 red[256];
    const int b = blockIdx.y, p = blockIdx.x;
    const int t = threadIdx.x;
    const int n0 = p * PBS;
    const int n  = n0 + t;
    const float* __restrict__ wp = g_w0 + b * NN;   // w4 lives in g_w0

    float w5 = 0.0f;
    if (n < NN) {
        const int deg = g_degU[b * NN + n];
        const unsigned short* __restrict__ pT = g_pT + (size_t)b * JMAX * NN + n;
        float sum = wp[n];
#pragma unroll
        for (int j = 0; j < JMAX; ++j)
            if (j < deg) sum += wp[pT[(size_t)j * NN]];
        w5 = sum;
    }
    w5s[t] = w5;
    __syncthreads();

    // pool rows n0..n0+255: part[d] = sum w5[row] * nodes[b][row][d]
    const int dslot = t & 31, rg = t >> 5;    // 32 f4-cols x 8 row-groups
    const int nrows = min(PBS, NN - n0);
    const float4* __restrict__ base = (const float4*)(nodes + (size_t)b * NN * ND);
    float4 aA = {0.f, 0.f, 0.f, 0.f}, aB = {0.f, 0.f, 0.f, 0.f};
    int row = rg;
    for (; row + 8 < nrows; row += 16) {
        const float wA = w5s[row], wB = w5s[row + 8];
        const float4 vA = base[(size_t)(n0 + row) * 32 + dslot];
        const float4 vB = base[(size_t)(n0 + row + 8) * 32 + dslot];
        aA.x += wA * vA.x; aA.y += wA * vA.y; aA.z += wA * vA.z; aA.w += wA * vA.w;
        aB.x += wB * vB.x; aB.y += wB * vB.y; aB.z += wB * vB.z; aB.w += wB * vB.w;
    }
    if (row < nrows) {
        const float wA = w5s[row];
        const float4 vA = base[(size_t)(n0 + row) * 32 + dslot];
        aA.x += wA * vA.x; aA.y += wA * vA.y; aA.z += wA * vA.z; aA.w += wA * vA.w;
    }
    float4 s4;
    s4.x = aA.x + aB.x; s4.y = aA.y + aB.y; s4.z = aA.z + aB.z; s4.w = aA.w + aB.w;
    red[t] = s4;
    __syncthreads();
    if (t < 32) {
        float4 s = red[t];
        for (int q = 1; q < 8; ++q) {
            const float4 o = red[q * 32 + t];
            s.x += o.x; s.y += o.y; s.z += o.z; s.w += o.w;
        }
        ((float4*)g_ppart)[((size_t)b * NPB + p) * 32 + t] = s;
    }
}

// ---- kernel 7: reduce NPB partials per batch + full head, one block ----
__global__ void reduceHeadK(const float* __restrict__ ptype,
                            const float* __restrict__ w1, const float* __restrict__ b1,
                            const float* __restrict__ w2, const float* __restrict__ b2,
                            const float* __restrict__ w3, const float* __restrict__ b3,
                            float* __restrict__ out) {
    __shared__ float sx[NB][ND + 1];
    __shared__ float h1s[NB][80];
    __shared__ float h2s[NB][80];
    const int t = threadIdx.x;          // 1024 == NB * ND
    const int b = t >> 7, d = t & 127;

    float s = 0.0f;
    for (int j = 0; j < NPB; ++j)
        s += g_ppart[((size_t)b * NPB + j) * ND + d];

    float y = logf(s);
    if (isnan(y)) y = 0.0f;             // nan -> 0
    y = fmaxf(y, 0.0f);                 // relu (folds -inf -> 0)
    sx[b][d] = y;
    __syncthreads();

    if (t < NB) {
        float fm = -INFINITY;
        for (int dd = 0; dd < ND; ++dd) {
            const float v = sx[t][dd];
            if (!isinf(v)) fm = fmaxf(fm, v);
        }
        for (int dd = 0; dd < ND; ++dd)
            if (isinf(sx[t][dd])) sx[t][dd] = fm;   // +inf -> finite_max
        sx[t][ND] = ptype[t];
    }
    __syncthreads();

    if (t < NB * 80) {
        const int bb = t / 80, j = t - bb * 80;
        float v = b1[j];
        for (int k = 0; k < ND + 1; ++k) v += sx[bb][k] * w1[k * 80 + j];
        h1s[bb][j] = v > 0.0f ? v : 0.01f * v;      // leaky_relu
    }
    __syncthreads();

    if (t < NB * 80) {
        const int bb = t / 80, j = t - bb * 80;
        float v = b2[j];
        for (int k = 0; k < 80; ++k) v += h1s[bb][k] * w2[k * 80 + j];
        h2s[bb][j] = v > 0.0f ? v : 0.01f * v;
    }
    __syncthreads();

    if (t < NB * 10) {
        const int bb = t / 10, j = t - bb * 10;
        float v = b3[j];
        for (int k = 0; k < 80; ++k) v += h2s[bb][k] * w3[k * 10 + j];
        out[bb * 10 + j] = v;
    }
}

extern "C" void kernel_launch(void* const* d_in, const int* in_sizes, int n_in,
                              void* d_out, int out_size, void* d_ws, size_t ws_size,
                              hipStream_t stream) {
    const float* nodes = (const float*)d_in[0];
    const float* ptype = (const float*)d_in[1];
    const float* w1    = (const float*)d_in[2];
    const float* b1    = (const float*)d_in[3];
    const float* w2    = (const float*)d_in[4];
    const float* b2    = (const float*)d_in[5];
    const float* w3    = (const float*)d_in[6];
    const float* b3    = (const float*)d_in[7];
    const int*   edges = (const int*)d_in[8];
    float* out = (float*)d_out;

    distK<<<NB * NCHUNK, 256, 0, stream>>>(edges);      // single edge read
    slotK<<<dim3(NG, NB), 1024, 0, stream>>>();         // slot table + deg + w1

    passHO<1><<<dim3(PNB, NB), 512, 0, stream>>>();     // pass 2: w1 -> w0
    passHO<0><<<dim3(PNB, NB), 512, 0, stream>>>();     // pass 3: w0 -> w1
    passHO<1><<<dim3(PNB, NB), 512, 0, stream>>>();     // pass 4: w1 -> w0

    pass5poolK<<<dim3(NPB, NB), PBS, 0, stream>>>(nodes);  // pass 5 + pool
    reduceHeadK<<<1, 1024, 0, stream>>>(ptype, w1, b1, w2, b2, w3, b3, out);
}

// Round 23
// 110.282 us; speedup vs baseline: 8.8794x; 1.0012x over previous
//
#include <hip/hip_runtime.h>
#include <cmath>

#define NB 8
#define NN 20000
#define ND 128
#define NE_TOT 192000   /* 3 edge sets * 64000 edges, contiguous per batch */

#define GSZ 640                     /* src nodes per group */
#define NG 32                       /* NG*GSZ = 20480 >= NN */
#define ECHUNK 8000                 /* edges per bucketing chunk */
#define NCHUNK 24                   /* NE_TOT / ECHUNK, exact */
#define CSUB 384                    /* per-(b,g,chunk) sub-slot capacity (+8.6 sigma) */
#define FIX (NCHUNK * CSUB)         /* 9216 entries per (b,g) */
#define KPT (FIX / 1024)            /* 9 loads per slot-build thread */
#define JMAX 40                     /* slots per node; P(deg>40) ~ 1e-13 */

#define PNB 157                     /* pass blocks: 157*128 = 20096 >= NN */
#define PBS 256                     /* rows per pool block */
#define NPB ((NN + PBS - 1) / PBS)  /* 79 */

// weight ping-pong + build metadata + packed bucket + ushort slot table + partials
__device__ float          g_w0[NB * NN];
__device__ float          g_w1[NB * NN];
__device__ int            g_ccnt[NB][NCHUNK][NG];          // 24.6 KB
__device__ unsigned int   g_bucket[(size_t)NB * NG * FIX]; // 9.4 MB (dst | srcl<<16)
__device__ unsigned short g_degU[NB * NN];                 // 320 KB
__device__ unsigned short g_pT[(size_t)NB * JMAX * NN];    // 12.8 MB: pT[b][j][n]=dst
__device__ float          g_ppart[NB * NPB * ND];          // 323 KB

// ---- kernel 1: bin edges in LDS, dump bucket with fully coalesced stores ----
__global__ void __launch_bounds__(256)
distK(const int* __restrict__ edges) {
    __shared__ unsigned sbuf[NG][CSUB];   // 49152 B staging
    __shared__ int cur[NG];
    const int b = blockIdx.x / NCHUNK, c = blockIdx.x % NCHUNK;
    const int t = threadIdx.x;  // 256
    if (t < NG) cur[t] = 0;
    __syncthreads();
    const int2* __restrict__ ep =
        (const int2*)edges + (size_t)b * NE_TOT + (size_t)c * ECHUNK;
    for (int i = t; i < ECHUNK; i += 256) {
        const int2 e = ep[i];                 // e.x = dst, e.y = src
        const int g = (unsigned)e.y / GSZ;
        const int pos = atomicAdd(&cur[g], 1);
        if (pos < CSUB)                       // P(overflow) ~ 1e-14; guard only
            sbuf[g][pos] = (unsigned)e.x | ((unsigned)(e.y - g * GSZ) << 16);
    }
    __syncthreads();
    // coalesced dump (unused cells = garbage, masked later by g_ccnt)
    const unsigned* __restrict__ s = &sbuf[0][0];
    for (int idx = t; idx < NG * CSUB; idx += 256) {
        const int g = idx / CSUB, pos = idx - g * CSUB;
        g_bucket[((size_t)(b * NG + g)) * FIX + c * CSUB + pos] = s[idx];
    }
    if (t < NG) g_ccnt[b][c][t] = min(cur[t], CSUB);
}

// ---- kernel 2: degree hist + slot table built in LDS, dumped coalesced ----
__global__ void __launch_bounds__(1024)
slotK() {
    __shared__ unsigned short tbl[JMAX][GSZ];   // 51200 B staging
    __shared__ int hist[GSZ];
    __shared__ int cur[GSZ];
    __shared__ int ccnt[NCHUNK];
    const int b = blockIdx.y, g = blockIdx.x;
    const int t = threadIdx.x;            // 1024

    const unsigned* __restrict__ bk = g_bucket + (size_t)(b * NG + g) * FIX + t;
    unsigned e[KPT];
#pragma unroll
    for (int k = 0; k < KPT; ++k) e[k] = bk[k * 1024];

    if (t < GSZ) { hist[t] = 0; cur[t] = 0; }
    if (t < NCHUNK) ccnt[t] = g_ccnt[b][t][g];
    __syncthreads();

    bool val[KPT];
#pragma unroll
    for (int k = 0; k < KPT; ++k) {
        const int p = k * 1024 + t;
        const int c = p / CSUB;           // const-div -> magic mul
        val[k] = (p - c * CSUB) < ccnt[c];
        if (val[k]) atomicAdd(&hist[e[k] >> 16], 1);
    }
    __syncthreads();

    if (t < GSZ) {
        const int node = g * GSZ + t;
        if (node < NN) {
            const int d = hist[t];
            g_degU[b * NN + node] = (unsigned short)min(d, JMAX);
            g_w1[b * NN + node]   = 1.0f + (float)d;   // pass 1 for free
        }
    }
    __syncthreads();

    // scatter into LDS table (cheap), not into global
#pragma unroll
    for (int k = 0; k < KPT; ++k)
        if (val[k]) {
            const int y = e[k] >> 16;
            const int j = atomicAdd(&cur[y], 1);
            if (j < JMAX)
                tbl[j][y] = (unsigned short)(e[k] & 0xFFFF);
        }
    __syncthreads();

    // coalesced dump, uint-granular; clamp last group's columns to NN
    const size_t gbase = (size_t)b * JMAX * NN + (size_t)g * GSZ;
    const int cols2 = min(GSZ, NN - g * GSZ) >> 1;   // uints per row (80 or 320)
    for (int idx = t; idx < JMAX * (GSZ / 2); idx += 1024) {
        const int j = idx / (GSZ / 2), q = idx - j * (GSZ / 2);
        if (q < cols2)
            ((unsigned*)(g_pT + gbase + (size_t)j * NN))[q] =
                ((const unsigned*)&tbl[j][0])[q];
    }
}

// ---- kernels 3-5: high-occupancy pass: 4 j-groups x 128 nodes per block ----
// All per-node sums are integer-valued -> exact in any order (deterministic).
template<int SRC>   // SRC=1: read g_w1 write g_w0; SRC=0: reverse
__global__ void __launch_bounds__(512)
passHO() {
    __shared__ float sh[512];
    const int b  = blockIdx.y;
    const int nl = threadIdx.x & 127;
    const int jg = threadIdx.x >> 7;      // 0..3
    const int n  = blockIdx.x * 128 + nl;
    const float* __restrict__ wp = (SRC ? g_w1 : g_w0) + b * NN;
    float* __restrict__ wn       = (SRC ? g_w0 : g_w1) + b * NN;

    float partial = 0.0f;
    if (n < NN) {
        const int deg = g_degU[b * NN + n];
        const unsigned short* __restrict__ pT = g_pT + (size_t)b * JMAX * NN + n;
#pragma unroll
        for (int jj = 0; jj < 10; ++jj) {
            const int j = jg + 4 * jj;
            if (j < deg) partial += wp[pT[(size_t)j * NN]];
        }
    }
    sh[threadIdx.x] = partial;
    __syncthreads();
    if (jg == 0 && n < NN)
        wn[n] = wp[n] + ((sh[nl] + sh[128 + nl]) + (sh[256 + nl] + sh[384 + nl]));
}

// ---- kernel 6: final pass (unchanged gather phase) + ILP-4 pool w/ preload ----
__global__ void __launch_bounds__(256)
pass5poolK(const float* __restrict__ nodes) {
    __shared__ float w5s[PBS];
    __shared__ __align__(16) float4 red[256];
    const int b = blockIdx.y, p = blockIdx.x;
    const int t = threadIdx.x;
    const int n0 = p * PBS;
    const int n  = n0 + t;
    const float* __restrict__ wp = g_w0 + b * NN;   // w4 lives in g_w0

    // --- preload first pool iteration (4 rows) BEFORE the gather phase ---
    // Their HBM latency drains at the same barrier as the gather loads (free
    // overlap). Rows rg..rg+24 are provably < nrows even for the 32-row tail.
    const int dslot = t & 31, rg = t >> 5;    // 32 f4-cols x 8 row-groups
    const float4* __restrict__ base = (const float4*)(nodes + (size_t)b * NN * ND);
    const float4 p0 = base[(size_t)(n0 + rg)      * 32 + dslot];
    const float4 p1 = base[(size_t)(n0 + rg + 8)  * 32 + dslot];
    const float4 p2 = base[(size_t)(n0 + rg + 16) * 32 + dslot];
    const float4 p3 = base[(size_t)(n0 + rg + 24) * 32 + dslot];

    // --- pass-5 gather phase (byte-identical to R21) ---
    float w5 = 0.0f;
    if (n < NN) {
        const int deg = g_degU[b * NN + n];
        const unsigned short* __restrict__ pT = g_pT + (size_t)b * JMAX * NN + n;
        float sum = wp[n];
#pragma unroll
        for (int j = 0; j < JMAX; ++j)
            if (j < deg) sum += wp[pT[(size_t)j * NN]];
        w5 = sum;
    }
    w5s[t] = w5;
    __syncthreads();

    // --- pool: 4 independent chains, rows {rg,+8,+16,+24} step 32 ---
    const int nrows = min(PBS, NN - n0);      // 256, or 32 for the last block
    float4 a0, a1, a2, a3;
    {
        const float w0v = w5s[rg],      w1v = w5s[rg + 8];
        const float w2v = w5s[rg + 16], w3v = w5s[rg + 24];
        a0.x = w0v * p0.x; a0.y = w0v * p0.y; a0.z = w0v * p0.z; a0.w = w0v * p0.w;
        a1.x = w1v * p1.x; a1.y = w1v * p1.y; a1.z = w1v * p1.z; a1.w = w1v * p1.w;
        a2.x = w2v * p2.x; a2.y = w2v * p2.y; a2.z = w2v * p2.z; a2.w = w2v * p2.w;
        a3.x = w3v * p3.x; a3.y = w3v * p3.y; a3.z = w3v * p3.z; a3.w = w3v * p3.w;
    }
    for (int row = rg + 32; row + 24 < nrows; row += 32) {
        const float w0v = w5s[row],      w1v = w5s[row + 8];
        const float w2v = w5s[row + 16], w3v = w5s[row + 24];
        const float4 v0 = base[(size_t)(n0 + row)      * 32 + dslot];
        const float4 v1 = base[(size_t)(n0 + row + 8)  * 32 + dslot];
        const float4 v2 = base[(size_t)(n0 + row + 16) * 32 + dslot];
        const float4 v3 = base[(size_t)(n0 + row + 24) * 32 + dslot];
        a0.x += w0v * v0.x; a0.y += w0v * v0.y; a0.z += w0v * v0.z; a0.w += w0v * v0.w;
        a1.x += w1v * v1.x; a1.y += w1v * v1.y; a1.z += w1v * v1.z; a1.w += w1v * v1.w;
        a2.x += w2v * v2.x; a2.y += w2v * v2.y; a2.z += w2v * v2.z; a2.w += w2v * v2.w;
        a3.x += w3v * v3.x; a3.y += w3v * v3.y; a3.z += w3v * v3.z; a3.w += w3v * v3.w;
    }
    float4 s4;
    s4.x = (a0.x + a1.x) + (a2.x + a3.x);
    s4.y = (a0.y + a1.y) + (a2.y + a3.y);
    s4.z = (a0.z + a1.z) + (a2.z + a3.z);
    s4.w = (a0.w + a1.w) + (a2.w + a3.w);
    red[t] = s4;
    __syncthreads();
    if (t < 32) {
        float4 s = red[t];
        for (int q = 1; q < 8; ++q) {
            const float4 o = red[q * 32 + t];
            s.x += o.x; s.y += o.y; s.z += o.z; s.w += o.w;
        }
        ((float4*)g_ppart)[((size_t)b * NPB + p) * 32 + t] = s;
    }
}

// ---- kernel 7: reduce NPB partials per batch + full head, one block ----
__global__ void reduceHeadK(const float* __restrict__ ptype,
                            const float* __restrict__ w1, const float* __restrict__ b1,
                            const float* __restrict__ w2, const float* __restrict__ b2,
                            const float* __restrict__ w3, const float* __restrict__ b3,
                            float* __restrict__ out) {
    __shared__ float sx[NB][ND + 1];
    __shared__ float h1s[NB][80];
    __shared__ float h2s[NB][80];
    const int t = threadIdx.x;          // 1024 == NB * ND
    const int b = t >> 7, d = t & 127;

    float s = 0.0f;
    for (int j = 0; j < NPB; ++j)
        s += g_ppart[((size_t)b * NPB + j) * ND + d];

    float y = logf(s);
    if (isnan(y)) y = 0.0f;             // nan -> 0
    y = fmaxf(y, 0.0f);                 // relu (folds -inf -> 0)
    sx[b][d] = y;
    __syncthreads();

    if (t < NB) {
        float fm = -INFINITY;
        for (int dd = 0; dd < ND; ++dd) {
            const float v = sx[t][dd];
            if (!isinf(v)) fm = fmaxf(fm, v);
        }
        for (int dd = 0; dd < ND; ++dd)
            if (isinf(sx[t][dd])) sx[t][dd] = fm;   // +inf -> finite_max
        sx[t][ND] = ptype[t];
    }
    __syncthreads();

    if (t < NB * 80) {
        const int bb = t / 80, j = t - bb * 80;
        float v = b1[j];
        for (int k = 0; k < ND + 1; ++k) v += sx[bb][k] * w1[k * 80 + j];
        h1s[bb][j] = v > 0.0f ? v : 0.01f * v;      // leaky_relu
    }
    __syncthreads();

    if (t < NB * 80) {
        const int bb = t / 80, j = t - bb * 80;
        float v = b2[j];
        for (int k = 0; k < 80; ++k) v += h1s[bb][k] * w2[k * 80 + j];
        h2s[bb][j] = v > 0.0f ? v : 0.01f * v;
    }
    __syncthreads();

    if (t < NB * 10) {
        const int bb = t / 10, j = t - bb * 10;
        float v = b3[j];
        for (int k = 0; k < 80; ++k) v += h2s[bb][k] * w3[k * 10 + j];
        out[bb * 10 + j] = v;
    }
}

extern "C" void kernel_launch(void* const* d_in, const int* in_sizes, int n_in,
                              void* d_out, int out_size, void* d_ws, size_t ws_size,
                              hipStream_t stream) {
    const float* nodes = (const float*)d_in[0];
    const float* ptype = (const float*)d_in[1];
    const float* w1    = (const float*)d_in[2];
    const float* b1    = (const float*)d_in[3];
    const float* w2    = (const float*)d_in[4];
    const float* b2    = (const float*)d_in[5];
    const float* w3    = (const float*)d_in[6];
    const float* b3    = (const float*)d_in[7];
    const int*   edges = (const int*)d_in[8];
    float* out = (float*)d_out;

    distK<<<NB * NCHUNK, 256, 0, stream>>>(edges);      // single edge read
    slotK<<<dim3(NG, NB), 1024, 0, stream>>>();         // slot table + deg + w1

    passHO<1><<<dim3(PNB, NB), 512, 0, stream>>>();     // pass 2: w1 -> w0
    passHO<0><<<dim3(PNB, NB), 512, 0, stream>>>();     // pass 3: w0 -> w1
    passHO<1><<<dim3(PNB, NB), 512, 0, stream>>>();     // pass 4: w1 -> w0

    pass5poolK<<<dim3(NPB, NB), PBS, 0, stream>>>(nodes);  // pass 5 + pool
    reduceHeadK<<<1, 1024, 0, stream>>>(ptype, w1, b1, w2, b2, w3, b3, out);
}